// Round 1
// 761.094 us; speedup vs baseline: 1.1708x; 1.1708x over previous
//
#include <hip/hip_runtime.h>
#include <math.h>

#define N_PTS 32768
#define DIM   512
#define K_CL  64
#define ITERS 10
#define EPS_F 1e-8f

typedef __attribute__((ext_vector_type(8))) short          short8v;
typedef __attribute__((ext_vector_type(8))) unsigned short ushort8v;
typedef __attribute__((ext_vector_type(4))) float          f32x4v;

__device__ __forceinline__ unsigned short f2bf(float f) {
    unsigned u = __builtin_bit_cast(unsigned, f);
    unsigned r = u + 0x7fffu + ((u >> 16) & 1u);
    return (unsigned short)(r >> 16);
}
__device__ __forceinline__ float bf2f(unsigned short h) {
    return __builtin_bit_cast(float, ((unsigned)h) << 16);
}

// ws layout (floats):
//   ct:      [0, 32768)       fp32 centers transposed ct[d*64+k] (final_dist)
//   (spare): [32768, 65536)
//   c2:      [65536, 65600)
//   cth:     ushort @ float 65600  (64x512 bf16-hi, row-major)
//   ctl:     ushort @ float 81984  (64x512 bf16-lo)
//   rcnt:    int    @ float 98368  (64 clusters x 8 regions)
//   assignv: int    @ float 98880  (32768)
//   part:    float  @ 131648       (64 x 8 x 512 region partial sums)

__global__ void init_centers(const float* __restrict__ x,
                             float* __restrict__ ct,
                             float* __restrict__ c2,
                             unsigned short* __restrict__ cth,
                             unsigned short* __restrict__ ctl) {
    int k = blockIdx.x;
    int t = threadIdx.x;
    float ssum = 0.f;
    for (int d = t; d < DIM; d += 256) {
        float v = x[k * DIM + d];
        ct[d * K_CL + k] = v;
        unsigned short h = f2bf(v);
        cth[k * DIM + d] = h;
        ctl[k * DIM + d] = f2bf(v - bf2f(h));
        ssum += v * v;
    }
    #pragma unroll
    for (int off = 32; off; off >>= 1) ssum += __shfl_down(ssum, off);
    __shared__ float red[4];
    if ((t & 63) == 0) red[t >> 6] = ssum;
    __syncthreads();
    if (t == 0) c2[k] = red[0] + red[1] + red[2] + red[3];
}

// ---------------------------------------------------------------------------
// MFMA assignment, one wave per 16 points. dot = xh*ch + xh*cl + xl*ch
// (bf16 split). Writes assign[p] only — NO atomics, fully deterministic.
// ---------------------------------------------------------------------------
__launch_bounds__(64)
__global__ void assign_mfma(const float* __restrict__ x,
                            const unsigned short* __restrict__ cth,
                            const unsigned short* __restrict__ ctl,
                            const float* __restrict__ c2,
                            int* __restrict__ assignv) {
    const int lane  = threadIdx.x;
    const int mbase = blockIdx.x * 16;
    const int mrow  = lane & 15;
    const int kgrp  = lane >> 4;

    const float* xr = x + (size_t)(mbase + mrow) * DIM + kgrp * 8;
    const unsigned short* cbh = cth + (size_t)mrow * DIM + kgrp * 8;
    const unsigned short* cbl = ctl + (size_t)mrow * DIM + kgrp * 8;

    f32x4v acc[4];
    acc[0] = acc[1] = acc[2] = acc[3] = (f32x4v){0.f, 0.f, 0.f, 0.f};

    float4 xraw[2][2];
    xraw[0][0] = *(const float4*)(xr);
    xraw[0][1] = *(const float4*)(xr + 4);

    int buf = 0;
    for (int ks = 0; ks < 16; ++ks) {
        if (ks < 15) {
            xraw[buf ^ 1][0] = *(const float4*)(xr + (ks + 1) * 32);
            xraw[buf ^ 1][1] = *(const float4*)(xr + (ks + 1) * 32 + 4);
        }
        short8v bh[4], bl[4];
        #pragma unroll
        for (int nt = 0; nt < 4; ++nt) {
            const size_t off = (size_t)nt * 16 * DIM + ks * 32;
            bh[nt] = *(const short8v*)(cbh + off);
            bl[nt] = *(const short8v*)(cbl + off);
        }
        short8v ah, al;
        {
            float fs[8] = {xraw[buf][0].x, xraw[buf][0].y,
                           xraw[buf][0].z, xraw[buf][0].w,
                           xraw[buf][1].x, xraw[buf][1].y,
                           xraw[buf][1].z, xraw[buf][1].w};
            ushort8v h, l;
            #pragma unroll
            for (int i = 0; i < 8; ++i) {
                unsigned short hh = f2bf(fs[i]);
                h[i] = hh;
                l[i] = f2bf(fs[i] - bf2f(hh));
            }
            ah = __builtin_bit_cast(short8v, h);
            al = __builtin_bit_cast(short8v, l);
        }
        #pragma unroll
        for (int nt = 0; nt < 4; ++nt) {
            acc[nt] = __builtin_amdgcn_mfma_f32_16x16x32_bf16(
                ah, bh[nt], acc[nt], 0, 0, 0);
            acc[nt] = __builtin_amdgcn_mfma_f32_16x16x32_bf16(
                ah, bl[nt], acc[nt], 0, 0, 0);
            acc[nt] = __builtin_amdgcn_mfma_f32_16x16x32_bf16(
                al, bh[nt], acc[nt], 0, 0, 0);
        }
        buf ^= 1;
    }

    float c2v[4];
    #pragma unroll
    for (int nt = 0; nt < 4; ++nt) c2v[nt] = c2[nt * 16 + mrow];

    #pragma unroll
    for (int r = 0; r < 4; ++r) {
        float bv = 1e30f; int bc = 0;
        #pragma unroll
        for (int nt = 0; nt < 4; ++nt) {
            float v = c2v[nt] - 2.0f * acc[nt][r];
            if (v < bv) { bv = v; bc = nt * 16 + mrow; }
        }
        #pragma unroll
        for (int m = 1; m < 16; m <<= 1) {
            float ov = __shfl_xor(bv, m);
            int   oc = __shfl_xor(bc, m);
            if (ov < bv || (ov == bv && oc < bc)) { bv = ov; bc = oc; }
        }
        if (mrow == 0) assignv[mbase + kgrp * 4 + r] = bc;
    }
}

// ---------------------------------------------------------------------------
// Fused build_lists + gather_part: one block per (cluster k, region pc).
// Phase 1-3 build the ordered member list in LDS (parallel ballots across
// 8 waves, wave-0 shuffle prefix over 64 chunk counts, ordered writes) --
// list contents identical (strictly ascending point order) to the old
// serial single-wave scan. Phase 4 gathers exactly as gather_part did
// (same per-thread accumulation order) -> part/rcnt bitwise identical.
// ---------------------------------------------------------------------------
__launch_bounds__(512)
__global__ void build_gather(const float* __restrict__ x,
                             const int* __restrict__ assignv,
                             int* __restrict__ rcnt,
                             float* __restrict__ part) {
    const int k    = blockIdx.x;
    const int pc   = blockIdx.y;
    const int t    = threadIdx.x;   // 0..511 (dim in phase 4)
    const int lane = t & 63;
    const int w    = t >> 6;        // wave 0..7
    const int p0   = pc * 4096;

    __shared__ int                lst[4096];
    __shared__ unsigned long long msk[64];
    __shared__ int                cnt[64];
    __shared__ int                basel[64];
    __shared__ int                ntot;

    // phase 1: per-chunk ballots (8 chunks of 64 points per wave)
    #pragma unroll
    for (int j = 0; j < 8; ++j) {
        const int chunk = w * 8 + j;
        const int a = assignv[p0 + chunk * 64 + lane];
        unsigned long long m = __ballot(a == k);
        if (lane == 0) { msk[chunk] = m; cnt[chunk] = __popcll(m); }
    }
    __syncthreads();

    // phase 2: exclusive prefix over the 64 chunk counts (wave 0)
    if (w == 0) {
        const int v = cnt[lane];
        int incl = v;
        #pragma unroll
        for (int off = 1; off < 64; off <<= 1) {
            int u = __shfl_up(incl, off);
            if (lane >= off) incl += u;
        }
        basel[lane] = incl - v;
        if (lane == 63) { ntot = incl; rcnt[k * 8 + pc] = incl; }
    }
    __syncthreads();

    // phase 3: ordered member writes into LDS list
    #pragma unroll
    for (int j = 0; j < 8; ++j) {
        const int chunk = w * 8 + j;
        const unsigned long long m = msk[chunk];
        if ((m >> lane) & 1ull) {
            const int pos = basel[chunk] +
                __popcll(m & ((1ull << lane) - 1ull));
            lst[pos] = p0 + chunk * 64 + lane;
        }
    }
    __syncthreads();

    // phase 4: gather, identical structure/order to old gather_part
    const int n = ntot;
    float acc = 0.f;
    int s = 0;
    for (; s + 8 <= n; s += 8) {
        int idx[8];
        #pragma unroll
        for (int q = 0; q < 8; ++q) idx[q] = lst[s + q];
        #pragma unroll
        for (int q = 0; q < 8; ++q) acc += x[(size_t)idx[q] * DIM + t];
    }
    for (; s < n; ++s) acc += x[(size_t)lst[s] * DIM + t];
    part[((size_t)k * 8 + pc) * DIM + t] = acc;
}

// Combine region partials in fixed ascending pc order (deterministic),
// divide, refresh fp32/bf16-split centers and c2.
__global__ void update_centers(float* __restrict__ ct,
                               const float* __restrict__ part,
                               const int* __restrict__ rcnt,
                               float* __restrict__ c2,
                               unsigned short* __restrict__ cth,
                               unsigned short* __restrict__ ctl) {
    int k = blockIdx.x;
    int t = threadIdx.x;
    int cnt = 0;
    #pragma unroll
    for (int pc = 0; pc < 8; ++pc) cnt += rcnt[k * 8 + pc];
    float fc = (float)cnt;
    float ssum = 0.f;
    for (int d = t; d < DIM; d += 256) {
        float v = ct[d * K_CL + k];
        if (cnt > 0) {
            float s = 0.f;
            #pragma unroll
            for (int pc = 0; pc < 8; ++pc)
                s += part[((size_t)k * 8 + pc) * DIM + d];
            v = s / fc;
        }
        ct[d * K_CL + k] = v;
        unsigned short h = f2bf(v);
        cth[k * DIM + d] = h;
        ctl[k * DIM + d] = f2bf(v - bf2f(h));
        ssum += v * v;
    }
    #pragma unroll
    for (int off = 32; off; off >>= 1) ssum += __shfl_down(ssum, off);
    __shared__ float red[4];
    if ((t & 63) == 0) red[t >> 6] = ssum;
    __syncthreads();
    if (t == 0) c2[k] = red[0] + red[1] + red[2] + red[3];
}

// ---------------------------------------------------------------------------
// Final distances via exact fp32 differencing (known-pass):
// d2 == 0 bitwise at any point equal to its center -> exact 1e8 entries.
// v2: 16 points/block, 2048 blocks x 128 thr -> 8 blocks/CU = 16 waves/CU
// (was 4). xs staged via XOR-swizzled global source (kq ^= row>>1) with
// linear LDS dest (global_load_lds constraint) + matching XOR on the read:
// the 4 rr-groups of a wave now hit distinct banks (was 4-way conflict).
// ---------------------------------------------------------------------------
#define DMA_T(tt, bb)                                                          \
    {                                                                          \
        _Pragma("unroll")                                                      \
        for (int q_ = 0; q_ < 4; ++q_) {                                       \
            __builtin_amdgcn_global_load_lds(                                  \
                (const __attribute__((address_space(1))) void*)                \
                    (ct + (tt) * 2048 + q_ * 512 + tid * 4),                   \
                (__attribute__((address_space(3))) void*)                      \
                    (&cs[bb][q_ * 512 + tid * 4]),                             \
                16, 0, 0);                                                     \
        }                                                                      \
        {                                                                      \
            const int row_ = tid >> 3;                                         \
            const int kq_  = (tid & 7) ^ ((row_ >> 1) & 7);                    \
            __builtin_amdgcn_global_load_lds(                                  \
                (const __attribute__((address_space(1))) void*)                \
                    (x + (size_t)(pbase + row_) * DIM +                        \
                     (tt) * 32 + kq_ * 4),                                     \
                (__attribute__((address_space(3))) void*)                      \
                    (&xs[bb][tid * 4]),                                        \
                16, 0, 0);                                                     \
        }                                                                      \
    }

#define LOADX(sl, kq)                                                          \
    {                                                                          \
        _Pragma("unroll")                                                      \
        for (int i_ = 0; i_ < 2; ++i_) {                                       \
            const int row_ = rr * 2 + i_;                                      \
            xv[sl][i_] = *(const float4*)(                                     \
                &xs[buf][(row_ * 8 + ((kq) ^ (row_ >> 1))) * 4]);              \
        }                                                                      \
    }

#define LOADC(sl, kq)                                                          \
    {                                                                          \
        _Pragma("unroll")                                                      \
        for (int j_ = 0; j_ < 4; ++j_)                                         \
            cv[sl][j_] = *(const float4*)(&cs[buf][((kq) * 4 + j_) * 64 +      \
                                                   c * 4]);                    \
    }

#define BODY_DIST(kq)                                                          \
    {                                                                          \
        if ((kq) < 7) { LOADX(((kq) + 1) & 1, (kq) + 1);                       \
                        LOADC(((kq) + 1) & 1, (kq) + 1); }                     \
        const float4 c0 = cv[(kq) & 1][0], c1 = cv[(kq) & 1][1];               \
        const float4 c2v = cv[(kq) & 1][2], c3 = cv[(kq) & 1][3];              \
        _Pragma("unroll")                                                      \
        for (int i = 0; i < 2; ++i) {                                          \
            const float4 xq = xv[(kq) & 1][i];                                 \
            float d0, d1, d2, d3;                                              \
            d0 = xq.x - c0.x;  acc[i][0] += d0 * d0;                           \
            d1 = xq.x - c0.y;  acc[i][1] += d1 * d1;                           \
            d2 = xq.x - c0.z;  acc[i][2] += d2 * d2;                           \
            d3 = xq.x - c0.w;  acc[i][3] += d3 * d3;                           \
            d0 = xq.y - c1.x;  acc[i][0] += d0 * d0;                           \
            d1 = xq.y - c1.y;  acc[i][1] += d1 * d1;                           \
            d2 = xq.y - c1.z;  acc[i][2] += d2 * d2;                           \
            d3 = xq.y - c1.w;  acc[i][3] += d3 * d3;                           \
            d0 = xq.z - c2v.x; acc[i][0] += d0 * d0;                           \
            d1 = xq.z - c2v.y; acc[i][1] += d1 * d1;                           \
            d2 = xq.z - c2v.z; acc[i][2] += d2 * d2;                           \
            d3 = xq.z - c2v.w; acc[i][3] += d3 * d3;                           \
            d0 = xq.w - c3.x;  acc[i][0] += d0 * d0;                           \
            d1 = xq.w - c3.y;  acc[i][1] += d1 * d1;                           \
            d2 = xq.w - c3.z;  acc[i][2] += d2 * d2;                           \
            d3 = xq.w - c3.w;  acc[i][3] += d3 * d3;                           \
        }                                                                      \
    }

__launch_bounds__(128, 4)
__global__ void final_dist(const float* __restrict__ x,
                           const float* __restrict__ ct,
                           float* __restrict__ out) {
    __shared__ float xs[2][512];    // 16 rows x 8 chunks x 4 floats, swizzled
    __shared__ float cs[2][2048];   // 32 dims x 64 clusters per t-step

    const int tid = threadIdx.x;
    const int pbase = blockIdx.x * 16;
    const int rr = tid >> 4;        // 0..7, two points each
    const int c  = tid & 15;        // 4 clusters each

    float4 xv[2][2];
    float4 cv[2][4];
    float acc[2][4] = {};

    DMA_T(0, 0);
    __syncthreads();

    int buf = 0;
    for (int t = 0; t < 16; ++t) {
        if (t < 15) DMA_T(t + 1, buf ^ 1);
        LOADX(0, 0); LOADC(0, 0);
        BODY_DIST(0); BODY_DIST(1); BODY_DIST(2); BODY_DIST(3);
        BODY_DIST(4); BODY_DIST(5); BODY_DIST(6); BODY_DIST(7);
        __syncthreads();
        buf ^= 1;
    }

    #pragma unroll
    for (int i = 0; i < 2; ++i) {
        int p = pbase + rr * 2 + i;
        float4 o;
        o.x = 1.0f / (sqrtf(acc[i][0]) + EPS_F);
        o.y = 1.0f / (sqrtf(acc[i][1]) + EPS_F);
        o.z = 1.0f / (sqrtf(acc[i][2]) + EPS_F);
        o.w = 1.0f / (sqrtf(acc[i][3]) + EPS_F);
        *(float4*)(out + (size_t)p * K_CL + c * 4) = o;
    }
}

extern "C" void kernel_launch(void* const* d_in, const int* in_sizes, int n_in,
                              void* d_out, int out_size, void* d_ws, size_t ws_size,
                              hipStream_t stream) {
    (void)in_sizes; (void)n_in; (void)out_size; (void)ws_size;
    const float* x = (const float*)d_in[0];
    float* ws      = (float*)d_ws;
    float* ct      = ws;
    float* c2      = ws + 65536;
    unsigned short* cth = (unsigned short*)(ws + 65600);
    unsigned short* ctl = (unsigned short*)(ws + 81984);
    int*   rcnt    = (int*)(ws + 98368);
    int*   assignv = (int*)(ws + 98880);
    float* part    = ws + 131648;
    float* out     = (float*)d_out;

    init_centers<<<64, 256, 0, stream>>>(x, ct, c2, cth, ctl);
    for (int it = 0; it < ITERS; ++it) {
        assign_mfma<<<2048, 64, 0, stream>>>(x, cth, ctl, c2, assignv);
        build_gather<<<dim3(64, 8), 512, 0, stream>>>(x, assignv, rcnt, part);
        update_centers<<<64, 256, 0, stream>>>(ct, part, rcnt, c2, cth, ctl);
    }
    final_dist<<<2048, 128, 0, stream>>>(x, ct, out);
}